// Round 8
// baseline (4218.533 us; speedup 1.0000x reference)
//
#include <hip/hip_runtime.h>
#include <hip/hip_bf16.h>

typedef unsigned short u16;
typedef unsigned int u32;

__device__ __forceinline__ float bf2f(u16 u) {
    u32 x = ((u32)u) << 16;
    float f;
    __builtin_memcpy(&f, &x, 4);
    return f;
}

__device__ __forceinline__ u16 f2bf(float f) {
    u32 u;
    __builtin_memcpy(&u, &f, 4);
    u += 0x7fffu + ((u >> 16) & 1u);
    return (u16)(u >> 16);
}

// ---------------------------------------------------------------------------
// f32 -> bf16 elementwise convert; 8 elements per thread.
// ---------------------------------------------------------------------------
__global__ __launch_bounds__(256) void f32_to_bf16(const float* __restrict__ in,
                                                   u16* __restrict__ out) {
    const int i = blockIdx.x * 256 + threadIdx.x;
    const float4* p = (const float4*)in;
    float4 a = p[i * 2], b = p[i * 2 + 1];
    ushort4 lo, hi;
    lo.x = f2bf(a.x); lo.y = f2bf(a.y); lo.z = f2bf(a.z); lo.w = f2bf(a.w);
    hi.x = f2bf(b.x); hi.y = f2bf(b.y); hi.z = f2bf(b.z); hi.w = f2bf(b.w);
    *(ushort4*)&out[i * 8] = lo;
    *(ushort4*)&out[i * 8 + 4] = hi;
}

// ---------------------------------------------------------------------------
// Naive GEMM oracle: out[M][N] = bf16(A[M][K] @ W[K][N] + bias), A bf16,
// W/bias f32, out bf16. grid (N/256, M/16), block 256.
// ---------------------------------------------------------------------------
__global__ __launch_bounds__(256) void gemm_naive(const u16* __restrict__ A,
                                                  const float* __restrict__ W,
                                                  const float* __restrict__ bias,
                                                  u16* __restrict__ out,
                                                  int N, int K) {
    const int col = blockIdx.x * 256 + threadIdx.x;
    const int row0 = blockIdx.y * 16;
    float acc[16];
    #pragma unroll
    for (int i = 0; i < 16; ++i) acc[i] = 0.f;

    for (int k = 0; k < K; ++k) {
        const float wv = W[(size_t)k * N + col];
        #pragma unroll
        for (int i = 0; i < 16; ++i)
            acc[i] = fmaf(bf2f(A[(size_t)(row0 + i) * K + k]), wv, acc[i]);
    }
    const float bv = bias[col];
    #pragma unroll
    for (int i = 0; i < 16; ++i)
        out[(size_t)(row0 + i) * N + col] = f2bf(acc[i] + bv);
}

// ---------------------------------------------------------------------------
// Same GEMM but writes FLOAT32 output — the round-8 probe: harness output
// buffer is hypothesized f32 (reference returns f32; dead-sentinel anomaly
// and pipeline-insensitive argmax error both confirm).
// ---------------------------------------------------------------------------
__global__ __launch_bounds__(256) void gemm_naive_f32out(const u16* __restrict__ A,
                                                         const float* __restrict__ W,
                                                         const float* __restrict__ bias,
                                                         float* __restrict__ out,
                                                         int N, int K) {
    const int col = blockIdx.x * 256 + threadIdx.x;
    const int row0 = blockIdx.y * 16;
    float acc[16];
    #pragma unroll
    for (int i = 0; i < 16; ++i) acc[i] = 0.f;

    for (int k = 0; k < K; ++k) {
        const float wv = W[(size_t)k * N + col];
        #pragma unroll
        for (int i = 0; i < 16; ++i)
            acc[i] = fmaf(bf2f(A[(size_t)(row0 + i) * K + k]), wv, acc[i]);
    }
    const float bv = bias[col];
    #pragma unroll
    for (int i = 0; i < 16; ++i)
        out[(size_t)(row0 + i) * N + col] = acc[i] + bv;
}

// ---------------------------------------------------------------------------
// Naive causal attention, PRINTED reference semantics (H1 swap reverted):
// kqv [B*T][3C] bf16: k = cols [0,1024), q = [1024,2048), v = [2048,3072).
// wei[i][j] = (k_i . q_j)/8, mask j<=i, softmax_j, out[i] = sum_j p_j v_j.
// grid (2048, 32), block 64. abuf[B*T][1024] bf16 (col h*64+d).
// ---------------------------------------------------------------------------
__global__ __launch_bounds__(64) void attn_naive(const u16* __restrict__ kqv,
                                                 u16* __restrict__ abuf) {
    __shared__ float sc[2048];
    __shared__ float kloc[64];
    const int lane = threadIdx.x;
    const int i = blockIdx.x;
    const int bh = blockIdx.y;
    const int b = bh >> 4, h = bh & 15;
    const u16* base = kqv + (size_t)b * 2048 * 3072;

    kloc[lane] = bf2f(base[(size_t)i * 3072 + h * 64 + lane]);
    __syncthreads();

    float mx = -3.0e38f;
    for (int j = lane; j <= i; j += 64) {
        const u16* qrow = base + (size_t)j * 3072 + 1024 + h * 64;
        float s = 0.f;
        #pragma unroll
        for (int d = 0; d < 64; ++d)
            s = fmaf(kloc[d], bf2f(qrow[d]), s);
        s *= 0.125f;
        sc[j] = s;
        mx = fmaxf(mx, s);
    }
    #pragma unroll
    for (int off = 32; off > 0; off >>= 1)
        mx = fmaxf(mx, __shfl_xor(mx, off));

    float sum = 0.f;
    for (int j = lane; j <= i; j += 64) {
        const float e = expf(sc[j] - mx);
        sc[j] = e;
        sum += e;
    }
    #pragma unroll
    for (int off = 32; off > 0; off >>= 1)
        sum += __shfl_xor(sum, off);
    __syncthreads();

    float acc = 0.f;
    for (int j = 0; j <= i; ++j)
        acc = fmaf(sc[j], bf2f(base[(size_t)j * 3072 + 2048 + h * 64 + lane]), acc);

    abuf[((size_t)b * 2048 + i) * 1024 + h * 64 + lane] = f2bf(acc / sum);
}

// ---------------------------------------------------------------------------
// ws: kqv [4096][3072] bf16 @ 0 (24 MB); abuf [4096][1024] bf16 @ 24MB (8 MB).
// xb (bf16 x) staged in the first 8 MB of d_out (f32 out buffer = 16 MB),
// dead before the proj gemm overwrites d_out with f32 results.
// ---------------------------------------------------------------------------
extern "C" void kernel_launch(void* const* d_in, const int* in_sizes, int n_in,
                              void* d_out, int out_size, void* d_ws, size_t ws_size,
                              hipStream_t stream) {
    const void *px = nullptr, *paw = nullptr, *pab = nullptr, *ppw = nullptr, *ppb = nullptr;
    for (int i = 0; i < n_in; ++i) {
        switch (in_sizes[i]) {
            case 4194304: px  = d_in[i]; break;  // x [2,2048,1024] f32
            case 3145728: paw = d_in[i]; break;  // c_attn_w [1024,3072] f32
            case 3072:    pab = d_in[i]; break;  // c_attn_b f32
            case 1048576: ppw = d_in[i]; break;  // c_proj_w [1024,1024] f32
            case 1024:    ppb = d_in[i]; break;  // c_proj_b f32
        }
    }
    if (!px || !paw || !pab || !ppw || !ppb) return;

    char* ws = (char*)d_ws;
    u16* kqv  = (u16*)(ws);                        // [4096][3072] bf16, 24 MB
    u16* abuf = (u16*)(ws + 25165824);             // [4096][1024] bf16, 8 MB
    float* out = (float*)d_out;                    // [4096][1024] f32 (probe)
    u16* xb   = (u16*)d_out;                       // bf16 x staged in d_out

    f32_to_bf16<<<2048, 256, 0, stream>>>((const float*)px, xb);
    gemm_naive<<<dim3(12, 256), 256, 0, stream>>>(xb, (const float*)paw, (const float*)pab, kqv, 3072, 1024);
    attn_naive<<<dim3(2048, 32), 64, 0, stream>>>(kqv, abuf);
    gemm_naive_f32out<<<dim3(4, 256), 256, 0, stream>>>(abuf, (const float*)ppw, (const float*)ppb, out, 1024, 1024);
}

// Round 9
// 241.881 us; speedup vs baseline: 17.4405x; 17.4405x over previous
//
#include <hip/hip_runtime.h>
#include <hip/hip_bf16.h>

typedef unsigned short u16;
typedef unsigned int u32;
typedef __attribute__((ext_vector_type(8))) short bf16x8;
typedef __attribute__((ext_vector_type(4))) float f32x4;

#define MFMA_BF16(a, b, c) __builtin_amdgcn_mfma_f32_16x16x32_bf16((a), (b), (c), 0, 0, 0)

__device__ __forceinline__ u16 f2bf(float f) {
    u32 u;
    __builtin_memcpy(&u, &f, 4);
    u += 0x7fffu + ((u >> 16) & 1u);
    return (u16)(u >> 16);
}

__device__ __forceinline__ void glds16(const void* g, void* l) {
    __builtin_amdgcn_global_load_lds(
        (__attribute__((address_space(1))) void*)(g),
        (__attribute__((address_space(3))) void*)(l),
        16, 0, 0);
}

// ---------------------------------------------------------------------------
// f32 -> bf16 elementwise convert; 8 elements per thread.
// ---------------------------------------------------------------------------
__global__ __launch_bounds__(256) void f32_to_bf16(const float* __restrict__ in,
                                                   u16* __restrict__ out) {
    const int i = blockIdx.x * 256 + threadIdx.x;
    const float4* p = (const float4*)in;
    float4 a = p[i * 2], b = p[i * 2 + 1];
    ushort4 lo, hi;
    lo.x = f2bf(a.x); lo.y = f2bf(a.y); lo.z = f2bf(a.z); lo.w = f2bf(a.w);
    hi.x = f2bf(b.x); hi.y = f2bf(b.y); hi.z = f2bf(b.z); hi.w = f2bf(b.w);
    *(ushort4*)&out[i * 8] = lo;
    *(ushort4*)&out[i * 8 + 4] = hi;
}

// ---------------------------------------------------------------------------
// Weight transpose + f32->bf16: in f32 [K][N] -> out bf16 [N][K]
// grid: (N/64, K/64), block 256
// ---------------------------------------------------------------------------
__global__ __launch_bounds__(256) void transpose_k(const float* __restrict__ in,
                                                   u16* __restrict__ out,
                                                   int K, int N) {
    __shared__ u16 tl[64][68];
    const int tid = threadIdx.x;
    const int n0 = blockIdx.x * 64, k0 = blockIdx.y * 64;
    #pragma unroll
    for (int it = 0; it < 4; ++it) {
        int idx = tid + it * 256;
        int r = idx >> 4, c4 = (idx & 15) * 4;
        float4 v = *(const float4*)&in[(size_t)(k0 + r) * N + n0 + c4];
        tl[r][c4 + 0] = f2bf(v.x); tl[r][c4 + 1] = f2bf(v.y);
        tl[r][c4 + 2] = f2bf(v.z); tl[r][c4 + 3] = f2bf(v.w);
    }
    __syncthreads();
    #pragma unroll
    for (int it = 0; it < 4; ++it) {
        int idx = tid + it * 256;
        int r = idx >> 4, c4 = (idx & 15) * 4;
        ushort4 v;
        v.x = tl[c4 + 0][r]; v.y = tl[c4 + 1][r];
        v.z = tl[c4 + 2][r]; v.w = tl[c4 + 3][r];
        *(ushort4*)&out[(size_t)(n0 + r) * K + k0 + c4] = v;
    }
}

// ---------------------------------------------------------------------------
// m97-style gemm_bt: C[M,N] = A[M,K]*BT[N,K]^T + bias, K=1024, bf16 A/BT,
// f32 bias. 128x128 tile, BK=32, 256 thr (2x2 waves, 4x4 16x16x32 MFMA),
// global_load_lds width-16 staging (proven identical to explicit: R2==R3).
// mode 0: scatter bf16 to kbuf[B,H,T,D], qbuf[B,H,T,D], vbuf[B,H,D,T]
// mode 1: f32 row-major outf[M,1024]  (harness output buffer is f32)
// ---------------------------------------------------------------------------
__global__ __launch_bounds__(256) void gemm_bt(const u16* __restrict__ A,
                                               const u16* __restrict__ BT,
                                               const float* __restrict__ bias,
                                               u16* __restrict__ out0,
                                               u16* __restrict__ out1,
                                               u16* __restrict__ out2,
                                               float* __restrict__ outf,
                                               int mode) {
    __shared__ u16 As[128 * 32];
    __shared__ u16 Bs[128 * 32];
    const int tid = threadIdx.x;
    const int w = tid >> 6, lane = tid & 63;
    const int c = lane & 15, qd = lane >> 4;
    const int wm = (w >> 1) * 64, wn = (w & 1) * 64;
    const int bm = blockIdx.x * 128, bn = blockIdx.y * 128;
    const int K = 1024;

    f32x4 acc[4][4];
    #pragma unroll
    for (int mt = 0; mt < 4; ++mt)
        #pragma unroll
        for (int nt = 0; nt < 4; ++nt)
            acc[mt][nt] = (f32x4){0.f, 0.f, 0.f, 0.f};

    const u16* aP = A + (size_t)(bm + (tid >> 2)) * K + (tid & 3) * 8;
    const u16* bP = BT + (size_t)(bn + (tid >> 2)) * K + (tid & 3) * 8;
    u16* lA0 = &As[tid * 8];
    u16* lA1 = &As[2048 + tid * 8];
    u16* lB0 = &Bs[tid * 8];
    u16* lB1 = &Bs[2048 + tid * 8];

    for (int kk = 0; kk < K; kk += 32) {
        glds16(aP + kk, lA0);
        glds16(aP + kk + 64 * K, lA1);
        glds16(bP + kk, lB0);
        glds16(bP + kk + 64 * K, lB1);
        __syncthreads();
        bf16x8 af[4], bfr[4];
        #pragma unroll
        for (int mt = 0; mt < 4; ++mt)
            af[mt] = *(const bf16x8*)&As[(wm + mt * 16 + c) * 32 + qd * 8];
        #pragma unroll
        for (int nt = 0; nt < 4; ++nt)
            bfr[nt] = *(const bf16x8*)&Bs[(wn + nt * 16 + c) * 32 + qd * 8];
        #pragma unroll
        for (int mt = 0; mt < 4; ++mt)
            #pragma unroll
            for (int nt = 0; nt < 4; ++nt)
                acc[mt][nt] = MFMA_BF16(af[mt], bfr[nt], acc[mt][nt]);
        __syncthreads();
    }

    #pragma unroll
    for (int nt = 0; nt < 4; ++nt) {
        const int coln = bn + wn + nt * 16 + c;
        const float bv = bias[coln];
        const int reg = coln >> 10;
        const int nr = coln & 1023;
        const int hh = nr >> 6;
        const int dd = nr & 63;
        #pragma unroll
        for (int mt = 0; mt < 4; ++mt) {
            #pragma unroll
            for (int r = 0; r < 4; ++r) {
                const int row = bm + wm + mt * 16 + qd * 4 + r;
                const float ov = acc[mt][nt][r] + bv;
                if (mode == 0) {
                    const u16 o = f2bf(ov);
                    const int b = row >> 11, t = row & 2047;
                    if (reg == 0)
                        out0[((b * 16 + hh) * 2048 + t) * 64 + dd] = o;
                    else if (reg == 1)
                        out1[((b * 16 + hh) * 2048 + t) * 64 + dd] = o;
                    else
                        out2[((b * 16 + hh) * 64 + dd) * 2048 + t] = o;
                } else {
                    outf[(size_t)row * 1024 + coln] = ov;
                }
            }
        }
    }
}

// ---------------------------------------------------------------------------
// MFMA flash attention. Printed reference: wei = K@Q^T (K rows = "queries").
// Per block: one (b,h), 128 i-rows; j-tiles of 64. Compute S^T = Q*K^T so the
// P fragment's C-regs are j-contiguous (packed ushort4 LDS writes; A-frag
// reads back aligned). V staged transposed ([B,H,D,T]). Online softmax.
// 4 waves; wave w owns i in [i0+32w, i0+32w+32).
// ---------------------------------------------------------------------------
__global__ __launch_bounds__(256) void attn_kernel(const u16* __restrict__ kbuf,
                                                   const u16* __restrict__ qbuf,
                                                   const u16* __restrict__ vtbuf,
                                                   u16* __restrict__ outb) {
    __shared__ u16 Ks[128 * 72];
    __shared__ u16 Qs[64 * 72];
    __shared__ u16 VTs[64 * 72];
    __shared__ u16 Ps[4][32 * 72];
    __shared__ float red[4][32];

    const int tid = threadIdx.x;
    const int w = tid >> 6, lane = tid & 63;
    const int c = lane & 15, qd = lane >> 4;

    const int iblk = 15 - (int)blockIdx.x;  // heavy blocks first
    const int i0 = iblk * 128;
    const int bh = blockIdx.y;
    const u16* kp = kbuf + (size_t)bh * (2048 * 64);
    const u16* qp = qbuf + (size_t)bh * (2048 * 64);
    const u16* vp = vtbuf + (size_t)bh * (64 * 2048);

    #pragma unroll
    for (int it = 0; it < 4; ++it) {
        int idx = tid + it * 256;
        int r = idx >> 3, col = (idx & 7) * 8;
        *(bf16x8*)&Ks[r * 72 + col] = *(const bf16x8*)&kp[(i0 + r) * 64 + col];
    }
    __syncthreads();

    const int iw = i0 + w * 32;
    bf16x8 kf[2][2];
    #pragma unroll
    for (int it = 0; it < 2; ++it)
        #pragma unroll
        for (int kt = 0; kt < 2; ++kt)
            kf[it][kt] = *(const bf16x8*)&Ks[(w * 32 + it * 16 + c) * 72 + kt * 32 + qd * 8];

    f32x4 oacc[2][4];
    #pragma unroll
    for (int mt = 0; mt < 2; ++mt)
        #pragma unroll
        for (int nt = 0; nt < 4; ++nt)
            oacc[mt][nt] = (f32x4){0.f, 0.f, 0.f, 0.f};

    float m_i[2] = {-3.0e38f, -3.0e38f};
    float l_i[2] = {0.f, 0.f};
    const float SCL = 0.18033688f;  // log2(e)/sqrt(64)
    const int nj = iblk * 2 + 2;

    for (int jj = 0; jj < nj; ++jj) {
        const int j0 = jj * 64;
        __syncthreads();
        #pragma unroll
        for (int it = 0; it < 2; ++it) {
            int idx = tid + it * 256;
            int r = idx >> 3, col = (idx & 7) * 8;
            *(bf16x8*)&Qs[r * 72 + col] = *(const bf16x8*)&qp[(j0 + r) * 64 + col];
            *(bf16x8*)&VTs[r * 72 + col] = *(const bf16x8*)&vp[r * 2048 + j0 + col];
        }
        __syncthreads();

        // S^T[j][i]: A = Q rows j, B = K^T, k-dim = d (64)
        f32x4 sacc[4][2];
        #pragma unroll
        for (int jt = 0; jt < 4; ++jt) {
            sacc[jt][0] = (f32x4){0.f, 0.f, 0.f, 0.f};
            sacc[jt][1] = (f32x4){0.f, 0.f, 0.f, 0.f};
            #pragma unroll
            for (int kt = 0; kt < 2; ++kt) {
                bf16x8 qf = *(const bf16x8*)&Qs[(jt * 16 + c) * 72 + kt * 32 + qd * 8];
                sacc[jt][0] = MFMA_BF16(qf, kf[0][kt], sacc[jt][0]);
                sacc[jt][1] = MFMA_BF16(qf, kf[1][kt], sacc[jt][1]);
            }
        }

        if (j0 + 63 > iw) {  // causal: valid iff j <= i
            #pragma unroll
            for (int jt = 0; jt < 4; ++jt)
                #pragma unroll
                for (int it = 0; it < 2; ++it)
                    #pragma unroll
                    for (int r = 0; r < 4; ++r) {
                        int j = j0 + jt * 16 + qd * 4 + r;
                        int i = iw + it * 16 + c;
                        if (j > i) sacc[jt][it][r] = -3.0e38f;
                    }
        }

        #pragma unroll
        for (int it = 0; it < 2; ++it) {
            float tmax = -3.0e38f;
            #pragma unroll
            for (int jt = 0; jt < 4; ++jt)
                #pragma unroll
                for (int r = 0; r < 4; ++r)
                    tmax = fmaxf(tmax, sacc[jt][it][r]);
            tmax = fmaxf(tmax, __shfl_xor(tmax, 16));
            tmax = fmaxf(tmax, __shfl_xor(tmax, 32));
            float mnew = fmaxf(m_i[it], tmax);
            float alpha = exp2f((m_i[it] - mnew) * SCL);
            m_i[it] = mnew;
            float ssum = 0.f;
            #pragma unroll
            for (int jt = 0; jt < 4; ++jt) {
                float p0 = exp2f((sacc[jt][it][0] - mnew) * SCL);
                float p1 = exp2f((sacc[jt][it][1] - mnew) * SCL);
                float p2 = exp2f((sacc[jt][it][2] - mnew) * SCL);
                float p3 = exp2f((sacc[jt][it][3] - mnew) * SCL);
                ssum += (p0 + p1) + (p2 + p3);
                ushort4 pk;
                pk.x = f2bf(p0); pk.y = f2bf(p1);
                pk.z = f2bf(p2); pk.w = f2bf(p3);
                *(ushort4*)&Ps[w][(it * 16 + c) * 72 + jt * 16 + qd * 4] = pk;
            }
            ssum += __shfl_xor(ssum, 16);
            ssum += __shfl_xor(ssum, 32);
            l_i[it] = l_i[it] * alpha + ssum;
            red[w][it * 16 + c] = alpha;
        }

        float ar[2][4];
        #pragma unroll
        for (int mt = 0; mt < 2; ++mt)
            #pragma unroll
            for (int r = 0; r < 4; ++r)
                ar[mt][r] = red[w][mt * 16 + qd * 4 + r];
        #pragma unroll
        for (int mt = 0; mt < 2; ++mt)
            #pragma unroll
            for (int nt = 0; nt < 4; ++nt)
                #pragma unroll
                for (int r = 0; r < 4; ++r)
                    oacc[mt][nt][r] *= ar[mt][r];

        #pragma unroll
        for (int kt = 0; kt < 2; ++kt) {
            bf16x8 pf0 = *(const bf16x8*)&Ps[w][c * 72 + kt * 32 + qd * 8];
            bf16x8 pf1 = *(const bf16x8*)&Ps[w][(16 + c) * 72 + kt * 32 + qd * 8];
            #pragma unroll
            for (int nt = 0; nt < 4; ++nt) {
                bf16x8 vf = *(const bf16x8*)&VTs[(nt * 16 + c) * 72 + kt * 32 + qd * 8];
                oacc[0][nt] = MFMA_BF16(pf0, vf, oacc[0][nt]);
                oacc[1][nt] = MFMA_BF16(pf1, vf, oacc[1][nt]);
            }
        }
    }

    red[w][c] = l_i[0];
    red[w][16 + c] = l_i[1];
    float li[2][4];
    #pragma unroll
    for (int mt = 0; mt < 2; ++mt)
        #pragma unroll
        for (int r = 0; r < 4; ++r)
            li[mt][r] = red[w][mt * 16 + qd * 4 + r];

    const int b = bh >> 4, hh = bh & 15;
    u16* op = outb + (size_t)b * (2048 * 1024) + hh * 64;
    #pragma unroll
    for (int mt = 0; mt < 2; ++mt) {
        #pragma unroll
        for (int r = 0; r < 4; ++r) {
            const int irow = iw + mt * 16 + qd * 4 + r;
            const float inv = 1.0f / li[mt][r];
            #pragma unroll
            for (int nt = 0; nt < 4; ++nt)
                op[(size_t)irow * 1024 + nt * 16 + c] = f2bf(oacc[mt][nt][r] * inv);
        }
    }
}

// ---------------------------------------------------------------------------
// ws plan (peak 32 MB):
//   kbuf@0 (8M) qbuf@8M (8M) vbuf@16M (8M) | wt_attn@24M (6M) -> abuf@24M (8M)
//   wt_proj@0 (2M, after attn frees kbuf). xb (bf16 x, 8 MB) staged in d_out
//   (f32 out = 16 MB); dead before proj gemm writes d_out.
// ---------------------------------------------------------------------------
extern "C" void kernel_launch(void* const* d_in, const int* in_sizes, int n_in,
                              void* d_out, int out_size, void* d_ws, size_t ws_size,
                              hipStream_t stream) {
    const void *px = nullptr, *paw = nullptr, *pab = nullptr, *ppw = nullptr, *ppb = nullptr;
    for (int i = 0; i < n_in; ++i) {
        switch (in_sizes[i]) {
            case 4194304: px  = d_in[i]; break;  // x [2,2048,1024] f32
            case 3145728: paw = d_in[i]; break;  // c_attn_w [1024,3072] f32
            case 3072:    pab = d_in[i]; break;  // c_attn_b f32
            case 1048576: ppw = d_in[i]; break;  // c_proj_w [1024,1024] f32
            case 1024:    ppb = d_in[i]; break;  // c_proj_b f32
        }
    }
    if (!px || !paw || !pab || !ppw || !ppb) return;

    char* ws = (char*)d_ws;
    u16* kbuf    = (u16*)(ws);                 // [2,16,2048,64]  8 MB
    u16* qbuf    = (u16*)(ws + 8388608);       // [2,16,2048,64]  8 MB
    u16* vbuf    = (u16*)(ws + 16777216);      // [2,16,64,2048]  8 MB (transposed)
    u16* wt_attn = (u16*)(ws + 25165824);      // [3072,1024]     6 MB
    u16* abuf    = (u16*)(ws + 25165824);      // [4096,1024]     8 MB (wt_attn dead)
    u16* wt_proj = (u16*)(ws);                 // [1024,1024]     2 MB (kbuf dead)
    float* out   = (float*)d_out;              // [4096,1024] f32
    u16* xb      = (u16*)d_out;                // bf16 x staged in d_out

    f32_to_bf16<<<2048, 256, 0, stream>>>((const float*)px, xb);
    transpose_k<<<dim3(48, 16), 256, 0, stream>>>((const float*)paw, wt_attn, 1024, 3072);
    gemm_bt<<<dim3(32, 24), 256, 0, stream>>>(xb, wt_attn, (const float*)pab,
                                              kbuf, qbuf, vbuf, nullptr, 0);
    attn_kernel<<<dim3(16, 32), 256, 0, stream>>>(kbuf, qbuf, vbuf, abuf);
    transpose_k<<<dim3(16, 16), 256, 0, stream>>>((const float*)ppw, wt_proj, 1024, 1024);
    gemm_bt<<<dim3(32, 8), 256, 0, stream>>>(abuf, wt_proj, (const float*)ppb,
                                             nullptr, nullptr, nullptr, out, 1);
}